// Round 5
// baseline (2948.424 us; speedup 1.0000x reference)
//
#include <hip/hip_runtime.h>

using u16 = unsigned short;
using u32 = unsigned int;

typedef short bf16x8 __attribute__((ext_vector_type(8)));
typedef float f32x4  __attribute__((ext_vector_type(4)));

__device__ __forceinline__ float bf2f(u16 u) {
    union { u32 u; float f; } v; v.u = ((u32)u) << 16; return v.f;
}
__device__ __forceinline__ u16 f2bf(float f) {
    union { float f; u32 u; } v; v.f = f;
    u32 r = v.u + 0x7FFFu + ((v.u >> 16) & 1u);   // RNE
    return (u16)(r >> 16);
}
__device__ __forceinline__ float fsig(float x)  { return 1.f / (1.f + __expf(-x)); }
__device__ __forceinline__ float ftanh(float x) { return 1.f - 2.f / (__expf(2.f * x) + 1.f); }

__device__ __forceinline__ uint4 pack8(const u16 h[8]) {
    uint4 u;
    u.x = (u32)h[0] | ((u32)h[1] << 16);
    u.y = (u32)h[2] | ((u32)h[3] << 16);
    u.z = (u32)h[4] | ((u32)h[5] << 16);
    u.w = (u32)h[6] | ((u32)h[7] << 16);
    return u;
}
__device__ __forceinline__ bf16x8 cvt8f(const float* p) {   // fp32x8 -> bf16 frag
    bf16x8 r;
    #pragma unroll
    for (int j = 0; j < 8; ++j) r[j] = (short)f2bf(p[j]);
    return r;
}

__device__ __forceinline__ void gld_lds16(const void* g, void* l) {
    // async global->LDS, 16B/lane; global src is PER-LANE addr, LDS dst is
    // wave-uniform base (+lane*16 added by HW). m97-proven pattern.
    __builtin_amdgcn_global_load_lds(
        (const __attribute__((address_space(1))) unsigned int*)g,
        (__attribute__((address_space(3))) unsigned int*)l, 16, 0, 0);
}

// ---------------------------------------------------------------------------
// Phase 1: x1[t][b][n] = feats[b][t][:] . W_ih1[n][:] + b_ih1[n] + b_hh1[n]
// fp32 split-bf16 3-pass (Ah*Bh + Ah*Bl + Al*Bh, error ~2^-17).
// M=32768, N=512, K=1024. 128x128 tile, BK=64. Layout [T, B, 512].
// Byte-for-byte the round-2 passing kernel.
// ---------------------------------------------------------------------------
__global__ __launch_bounds__(256) void x1_gemm(
    const float* __restrict__ feats, const float* __restrict__ Wih1,
    const float* __restrict__ bih1, const float* __restrict__ bhh1,
    float* __restrict__ x1p)
{
    __shared__ uint4 a_hi[128 * 8];
    __shared__ uint4 a_lo[128 * 8];
    __shared__ uint4 b_hi[128 * 8];
    __shared__ uint4 b_lo[128 * 8];
    const int tid  = threadIdx.x;
    const int lane = tid & 63, wave = tid >> 6;
    const int m0 = blockIdx.x * 128, n0 = blockIdx.y * 128;
    const int wm = (wave >> 1) * 64, wn = (wave & 1) * 64;
    const int lr = lane & 15, lk = lane >> 4;

    f32x4 acc[4][4] = {};

    for (int kt = 0; kt < 1024; kt += 64) {
        __syncthreads();
        #pragma unroll
        for (int it = 0; it < 4; ++it) {
            int idx = tid + it * 256;            // 0..1023
            int row = idx >> 3, c8 = idx & 7;
            int sw  = (row << 3) | (c8 ^ (row & 7));
            size_t offA = (size_t)(m0 + row) * 1024 + kt + c8 * 8;
            size_t offB = (size_t)(n0 + row) * 1024 + kt + c8 * 8;
            {
                const float* p = feats + offA;
                float4 v0 = *reinterpret_cast<const float4*>(p);
                float4 v1 = *reinterpret_cast<const float4*>(p + 4);
                float av[8] = {v0.x, v0.y, v0.z, v0.w, v1.x, v1.y, v1.z, v1.w};
                u16 h[8], l[8];
                #pragma unroll
                for (int j = 0; j < 8; ++j) {
                    h[j] = f2bf(av[j]);
                    l[j] = f2bf(av[j] - bf2f(h[j]));
                }
                a_hi[sw] = pack8(h);
                a_lo[sw] = pack8(l);
            }
            {
                const float* p = Wih1 + offB;
                float4 v0 = *reinterpret_cast<const float4*>(p);
                float4 v1 = *reinterpret_cast<const float4*>(p + 4);
                float bv[8] = {v0.x, v0.y, v0.z, v0.w, v1.x, v1.y, v1.z, v1.w};
                u16 h[8], l[8];
                #pragma unroll
                for (int j = 0; j < 8; ++j) {
                    h[j] = f2bf(bv[j]);
                    l[j] = f2bf(bv[j] - bf2f(h[j]));
                }
                b_hi[sw] = pack8(h);
                b_lo[sw] = pack8(l);
            }
        }
        __syncthreads();
        for (int s = 0; s < 3; ++s) {        // hi*hi, hi*lo, lo*hi
            const uint4* ab = (s == 2) ? a_lo : a_hi;
            const uint4* bb = (s == 1) ? b_lo : b_hi;
            #pragma unroll
            for (int kc = 0; kc < 2; ++kc) {
                bf16x8 af[4], bfr[4];
                #pragma unroll
                for (int i = 0; i < 4; ++i) {
                    int row = wm + i * 16 + lr;
                    af[i] = *reinterpret_cast<const bf16x8*>(&ab[(row << 3) | ((kc * 4 + lk) ^ (row & 7))]);
                }
                #pragma unroll
                for (int j = 0; j < 4; ++j) {
                    int row = wn + j * 16 + lr;
                    bfr[j] = *reinterpret_cast<const bf16x8*>(&bb[(row << 3) | ((kc * 4 + lk) ^ (row & 7))]);
                }
                #pragma unroll
                for (int i = 0; i < 4; ++i)
                    #pragma unroll
                    for (int j = 0; j < 4; ++j)
                        acc[i][j] = __builtin_amdgcn_mfma_f32_16x16x32_bf16(af[i], bfr[j], acc[i][j], 0, 0, 0);
            }
        }
    }
    // Epilogue: D row=(lane>>4)*4+q, col=lane&15. Store permuted to [T,B,512].
    #pragma unroll
    for (int j = 0; j < 4; ++j) {
        int n = n0 + wn + j * 16 + lr;
        float bias = bih1[n] + bhh1[n];
        #pragma unroll
        for (int i = 0; i < 4; ++i) {
            #pragma unroll
            for (int q = 0; q < 4; ++q) {
                int m = m0 + wm + i * 16 + lk * 4 + q;
                int b = m >> 9, t = m & 511;
                size_t o = ((size_t)(t * 64 + b)) * 512 + n;
                x1p[o] = acc[i][j][q] + bias;
            }
        }
    }
}

// ---------------------------------------------------------------------------
// Phase 2: FULLY FUSED scan. 4 blocks x 512 thr; block bg owns batch rows
// bg*16..+15 and computes BOTH layers. ZERO cross-block communication ->
// deterministic, replay-safe (round-4 proven). Per step r (one barrier):
//   read a1 = h1(r) frags (LDS, swizzled);
//   stage x1(r+2) -> LDS x-buffer (global_load_lds, m97 pattern);
//   acc2 = sum_kc a1*wa  + sum_kc a2*wb   (layer-2 pre-acts)
//   acch = sum_kc a1*wf                    (layer-1(r+1) pre-acts)
//   gates-L2 -> h2(r) (LDS bf16) + out (fp32);
//   gates-L1 (acch + x1(r+1) from LDS) -> h1(r+1) (LDS bf16);
//   barrier.
// ROUND-5 CHANGE: W_hh2 (wb) now persistent in VGPRs like wf/wa (192 regs
// of weights; accumulators live in AGPRs — unified file, 2 waves/SIMD).
// Round-4's per-step L1-missing L2 fragment loads of W_hh2 sat INSIDE the
// MFMA dependency chain (~2000 cyc/step); this removes them entirely.
// MFMA accumulation order and all rounding identical to round-4 (passing).
// ---------------------------------------------------------------------------
__global__ __launch_bounds__(512) void lstm_fused(
    const float* __restrict__ Whh1, const float* __restrict__ Wih2,
    const float* __restrict__ Whh2, const float* __restrict__ bih2,
    const float* __restrict__ bhh2, const float* __restrict__ x1p,
    float* __restrict__ out)
{
    __shared__ __align__(16) char smem[81920];
    // [0, 65536): x1 tile ping-pong, 2 x [16][512] f32 (x1(t) in buf t&1)
    // [65536, 73728): h1 ping-pong 2 x 4096   (h1(t) in buf t&1)
    // [73728, 81920): h2 ping-pong 2 x 4096   (h2(t) in buf t&1)
    char* xb  = smem;
    char* h1b = smem + 65536;
    char* h2b = smem + 73728;

    const int tid = threadIdx.x;
    const int wv = tid >> 6, ln = tid & 63;
    const int lr = ln & 15, lk = ln >> 4;
    const int bg = blockIdx.x;
    const int colP = wv * 16 + lr;       // hidden col j
    const int rowB = lk * 4;             // batch row base (q adds 0..3)

    // persistent weights: B[k][n]=W[n][k]; lane holds n=(G,wv,lr), k=kc*32+lk*8
    bf16x8 wf[4][4], wa[4][4], wb[4][4];
    float b2v[4];
    #pragma unroll
    for (int G = 0; G < 4; ++G) {
        int n = G * 128 + colP;
        #pragma unroll
        for (int kc = 0; kc < 4; ++kc) {
            wf[G][kc] = cvt8f(Whh1 + n * 128 + kc * 32 + lk * 8);
            wa[G][kc] = cvt8f(Wih2 + n * 128 + kc * 32 + lk * 8);
            wb[G][kc] = cvt8f(Whh2 + n * 128 + kc * 32 + lk * 8);
        }
        b2v[G] = bih2[n] + bhh2[n];
    }

    // zero h2 buf[1] (h2(-1), read at r=0)
    for (int i = tid; i < 1024; i += 512) ((u32*)(h2b + 4096))[i] = 0;

    // stage x1(0) -> xbuf[0]
    {
        const float* s = x1p + (size_t)(bg * 16) * 512 + wv * 1024 + ln * 4;
        char* d = xb + wv * 4096;
        #pragma unroll
        for (int i = 0; i < 4; ++i) gld_lds16(s + i * 256, d + i * 1024);
    }
    __syncthreads();   // x1(0) + h2-zero visible

    float c1[4] = {0.f, 0.f, 0.f, 0.f}, c2[4] = {0.f, 0.f, 0.f, 0.f};

    // --- prologue: h1(0) = gates(x1(0)) (acc = 0 exactly) ---
    #pragma unroll
    for (int q = 0; q < 4; ++q) {
        const float* xr = (const float*)(xb + (rowB + q) * 2048);
        float pi = xr[0 * 128 + colP];
        float pf = xr[1 * 128 + colP];
        float pg = xr[2 * 128 + colP];
        float po = xr[3 * 128 + colP];
        float ig = fsig(pi), fg = fsig(pf), gg = ftanh(pg), og = fsig(po);
        c1[q] = fg * c1[q] + ig * gg;
        float h = og * ftanh(c1[q]);
        int row = rowB + q;
        *(u16*)(h1b + row * 256 + ((((colP >> 3) ^ row) & 15) << 4) + (colP & 7) * 2)
            = f2bf(h);
    }
    // stage x1(1) -> xbuf[1]
    {
        const float* s = x1p + (size_t)(64 + bg * 16) * 512 + wv * 1024 + ln * 4;
        char* d = xb + 32768 + wv * 4096;
        #pragma unroll
        for (int i = 0; i < 4; ++i) gld_lds16(s + i * 256, d + i * 1024);
    }
    __syncthreads();   // h1(0) readable; x1(1) staged (vmcnt drained)

    for (int r = 0; r < 512; ++r) {
        const char* h1rd = h1b + ((r & 1) << 12);          // h1(r)
        char*       h1wr = h1b + (((r + 1) & 1) << 12);    // h1(r+1)
        const char* h2rd = h2b + (((r + 1) & 1) << 12);    // h2(r-1)
        char*       h2wr = h2b + ((r & 1) << 12);          // h2(r)
        const char* xrd  = xb  + (((r + 1) & 1) << 15);    // x1(r+1)

        // a1 frags = h1(r)
        bf16x8 a1[4];
        #pragma unroll
        for (int kc = 0; kc < 4; ++kc)
            a1[kc] = *(const bf16x8*)(h1rd + lr * 256 + ((((kc * 4 + lk) ^ lr) & 15) << 4));

        // stage x1(r+2) -> xbuf[r&1] (latency hides under this whole phase)
        if (r + 2 < 512) {
            const float* s = x1p + (size_t)((r + 2) * 64 + bg * 16) * 512 + wv * 1024 + ln * 4;
            char* d = xb + ((r & 1) << 15) + wv * 4096;
            #pragma unroll
            for (int i = 0; i < 4; ++i) gld_lds16(s + i * 256, d + i * 1024);
        }

        f32x4 acc2[4] = {}, acch[4] = {};
        // layer-2: a1*wa then a2*wb (round-2/4 order)
        #pragma unroll
        for (int kc = 0; kc < 4; ++kc)
            #pragma unroll
            for (int G = 0; G < 4; ++G)
                acc2[G] = __builtin_amdgcn_mfma_f32_16x16x32_bf16(a1[kc], wa[G][kc], acc2[G], 0, 0, 0);
        #pragma unroll
        for (int kc = 0; kc < 4; ++kc) {
            bf16x8 a2 = *(const bf16x8*)(h2rd + lr * 256 + ((((kc * 4 + lk) ^ lr) & 15) << 4));
            #pragma unroll
            for (int G = 0; G < 4; ++G)
                acc2[G] = __builtin_amdgcn_mfma_f32_16x16x32_bf16(a2, wb[G][kc], acc2[G], 0, 0, 0);
        }
        // layer-1(r+1): a1*wf
        #pragma unroll
        for (int kc = 0; kc < 4; ++kc)
            #pragma unroll
            for (int G = 0; G < 4; ++G)
                acch[G] = __builtin_amdgcn_mfma_f32_16x16x32_bf16(a1[kc], wf[G][kc], acch[G], 0, 0, 0);

        // gates L2 -> h2(r) (LDS) + out (fp32)
        float* orow = out + ((size_t)(bg * 16 + rowB) * 512 + r) * 128 + colP;
        #pragma unroll
        for (int q = 0; q < 4; ++q) {
            float pi = acc2[0][q] + b2v[0];
            float pf = acc2[1][q] + b2v[1];
            float pg = acc2[2][q] + b2v[2];
            float po = acc2[3][q] + b2v[3];
            float ig = fsig(pi), fg = fsig(pf), gg = ftanh(pg), og = fsig(po);
            c2[q] = fg * c2[q] + ig * gg;
            float h = og * ftanh(c2[q]);
            int row = rowB + q;
            *(u16*)(h2wr + row * 256 + ((((colP >> 3) ^ row) & 15) << 4) + (colP & 7) * 2)
                = f2bf(h);
            orow[(size_t)q * 512 * 128] = h;
        }
        // gates L1 -> h1(r+1) using x1(r+1) from LDS
        if (r + 1 < 512) {
            #pragma unroll
            for (int q = 0; q < 4; ++q) {
                const float* xr = (const float*)(xrd + (rowB + q) * 2048);
                float pi = acch[0][q] + xr[0 * 128 + colP];
                float pf = acch[1][q] + xr[1 * 128 + colP];
                float pg = acch[2][q] + xr[2 * 128 + colP];
                float po = acch[3][q] + xr[3 * 128 + colP];
                float ig = fsig(pi), fg = fsig(pf), gg = ftanh(pg), og = fsig(po);
                c1[q] = fg * c1[q] + ig * gg;
                float h = og * ftanh(c1[q]);
                int row = rowB + q;
                *(u16*)(h1wr + row * 256 + ((((colP >> 3) ^ row) & 15) << 4) + (colP & 7) * 2)
                    = f2bf(h);
            }
        }
        __syncthreads();   // drains LDS writes + x-stage vmcnt; next step safe
    }
}

// ---------------------------------------------------------------------------
extern "C" void kernel_launch(void* const* d_in, const int* in_sizes, int n_in,
                              void* d_out, int out_size, void* d_ws, size_t ws_size,
                              hipStream_t stream)
{
    const float* feats = (const float*)d_in[0];
    const float* Wih1  = (const float*)d_in[1];
    const float* Whh1  = (const float*)d_in[2];
    const float* bih1  = (const float*)d_in[3];
    const float* bhh1  = (const float*)d_in[4];
    const float* Wih2  = (const float*)d_in[5];
    const float* Whh2  = (const float*)d_in[6];
    const float* bih2  = (const float*)d_in[7];
    const float* bhh2  = (const float*)d_in[8];
    float* out = (float*)d_out;

    const size_t x1b = (size_t)32768 * 512 * 4;    // 64 MB, [T,B,512] f32
    if (ws_size < x1b) return;

    char* ws   = (char*)d_ws;
    float* x1p = (float*)ws;

    x1_gemm<<<dim3(256, 4), 256, 0, stream>>>(feats, Wih1, bih1, bhh1, x1p);
    lstm_fused<<<4, 512, 0, stream>>>(Whh1, Wih2, Whh2, bih2, bhh2, x1p, out);
    (void)in_sizes; (void)n_in; (void)out_size;
}